// Round 9
// baseline (191.381 us; speedup 1.0000x reference)
//
#include <hip/hip_runtime.h>
#include <math.h>

#define BATCH 32
#define NC    1024
#define NHID  512
#define NH    56
#define NW    56
#define HWSZ  3136   // 56*56
#define HW4   784    // HWSZ/4 (= 56 rows * 14 float4/row)

typedef float nfloat4 __attribute__((ext_vector_type(4)));

__device__ __forceinline__ float gelu_exact(float x) {
    return 0.5f * x * (1.0f + erff(x * 0.7071067811865476f));
}

// ---------------------------------------------------------------------------
// Kernel 1: GAP. One WAVE per (b,c) row — no LDS, no barriers. NT loads.
// ---------------------------------------------------------------------------
__global__ __launch_bounds__(256) void gap_kernel(const float* __restrict__ x,
                                                  float* __restrict__ y) {
    const int row  = (blockIdx.x << 2) | (threadIdx.x >> 6); // 4 waves/block
    const int lane = threadIdx.x & 63;
    const nfloat4* xr = (const nfloat4*)(x + (size_t)row * HWSZ);

    float s = 0.f;
#pragma unroll
    for (int it = 0; it < 12; ++it) {
        nfloat4 v = __builtin_nontemporal_load(xr + lane + (it << 6));
        s += (v.x + v.y) + (v.z + v.w);
    }
    if (lane < 16) {
        nfloat4 v = __builtin_nontemporal_load(xr + 768 + lane);
        s += (v.x + v.y) + (v.z + v.w);
    }
#pragma unroll
    for (int off = 32; off > 0; off >>= 1) s += __shfl_down(s, off);
    if (lane == 0) y[row] = s * (1.0f / 3136.0f);
}

// ---------------------------------------------------------------------------
// Kernel 2: FUSED MLP. One block per batch, 1024 threads, 3 phases:
//   fc1: h = gelu(y@W1)   — 128 float4-cols x 8-way split-K
//   fc2: yp = gelu(h@W2)  — 256 float4-cols x 4-way split-K
//   ab:  A = yp@WA+bA, Bv = yp@WB+bB — 64 lanes x 16-way split-K
// All intermediates live in LDS; weights are L2-hot (4.2 MB total).
// ---------------------------------------------------------------------------
__global__ __launch_bounds__(1024) void mlp_kernel(
    const float* __restrict__ y,  const float* __restrict__ W1,
    const float* __restrict__ W2, const float* __restrict__ WA,
    const float* __restrict__ bA, const float* __restrict__ WB,
    const float* __restrict__ bB, float* __restrict__ AB) {
    const int b = blockIdx.x;
    const int t = threadIdx.x;

    __shared__ float   sy[NC];
    __shared__ float   sh[NHID];
    __shared__ float   syp[NC];
    __shared__ nfloat4 part[1024];     // 16 KiB, reused by fc1/fc2
    __shared__ float   partA[1024];
    __shared__ float   partB[1024];

    sy[t] = y[b * NC + t];
    __syncthreads();

    // ---- fc1: 512 outputs ----
    {
        const int lane = t & 127;
        const int j0   = lane * 4;
        const int ks   = (t >> 7) * 128;          // 8 slices x 128 rows
        nfloat4 acc0 = {0.f, 0.f, 0.f, 0.f};
        nfloat4 acc1 = {0.f, 0.f, 0.f, 0.f};
        const float* wp = W1 + (size_t)ks * NHID + j0;
#pragma unroll 4
        for (int c = 0; c < 128; c += 2) {
            nfloat4 w0 = *(const nfloat4*)(wp + (size_t)(c + 0) * NHID);
            nfloat4 w1 = *(const nfloat4*)(wp + (size_t)(c + 1) * NHID);
            acc0 += sy[ks + c + 0] * w0;
            acc1 += sy[ks + c + 1] * w1;
        }
        part[t] = acc0 + acc1;
    }
    __syncthreads();
    if (t < 128) {
        nfloat4 s = part[t];
#pragma unroll
        for (int g = 1; g < 8; ++g) s += part[g * 128 + t];
        sh[t * 4 + 0] = gelu_exact(s.x);
        sh[t * 4 + 1] = gelu_exact(s.y);
        sh[t * 4 + 2] = gelu_exact(s.z);
        sh[t * 4 + 3] = gelu_exact(s.w);
    }
    __syncthreads();

    // ---- fc2: 1024 outputs ----
    {
        const int lane = t & 255;
        const int c0   = lane * 4;
        const int js   = (t >> 8) * 128;          // 4 slices x 128 rows
        nfloat4 acc0 = {0.f, 0.f, 0.f, 0.f};
        nfloat4 acc1 = {0.f, 0.f, 0.f, 0.f};
        const float* wp = W2 + (size_t)js * NC + c0;
#pragma unroll 4
        for (int jj = 0; jj < 128; jj += 2) {
            nfloat4 w0 = *(const nfloat4*)(wp + (size_t)(jj + 0) * NC);
            nfloat4 w1 = *(const nfloat4*)(wp + (size_t)(jj + 1) * NC);
            acc0 += sh[js + jj + 0] * w0;
            acc1 += sh[js + jj + 1] * w1;
        }
        part[t] = acc0 + acc1;
    }
    __syncthreads();
    if (t < 256) {
        nfloat4 s = part[t];
#pragma unroll
        for (int g = 1; g < 4; ++g) s += part[g * 256 + t];
        syp[t * 4 + 0] = gelu_exact(s.x);
        syp[t * 4 + 1] = gelu_exact(s.y);
        syp[t * 4 + 2] = gelu_exact(s.z);
        syp[t * 4 + 3] = gelu_exact(s.w);
    }
    __syncthreads();

    // ---- ab: A (56) and Bv (56) ----
    {
        const int i  = t & 63;
        const int ks = (t >> 6) * 64;             // 16 slices x 64 rows
        float a0 = 0.f, a1 = 0.f, a2 = 0.f, a3 = 0.f;
        float b0 = 0.f, b1 = 0.f, b2 = 0.f, b3 = 0.f;
        if (i < NH) {
            const float* wa = WA + (size_t)ks * NH + i;
            const float* wb = WB + (size_t)ks * NW + i;
            for (int c = 0; c < 64; c += 4) {
                a0 += syp[ks + c + 0] * wa[(size_t)(c + 0) * NH];
                a1 += syp[ks + c + 1] * wa[(size_t)(c + 1) * NH];
                a2 += syp[ks + c + 2] * wa[(size_t)(c + 2) * NH];
                a3 += syp[ks + c + 3] * wa[(size_t)(c + 3) * NH];
                b0 += syp[ks + c + 0] * wb[(size_t)(c + 0) * NW];
                b1 += syp[ks + c + 1] * wb[(size_t)(c + 1) * NW];
                b2 += syp[ks + c + 2] * wb[(size_t)(c + 2) * NW];
                b3 += syp[ks + c + 3] * wb[(size_t)(c + 3) * NW];
            }
        }
        partA[t] = (a0 + a1) + (a2 + a3);
        partB[t] = (b0 + b1) + (b2 + b3);
    }
    __syncthreads();
    if (t < NH) {
        float sa = bA[t], sb = bB[t];
#pragma unroll
        for (int g = 0; g < 16; ++g) {
            sa += partA[g * 64 + t];
            sb += partB[g * 64 + t];
        }
        AB[b * 128 + t] = sa;
        AB[b * 128 + 64 + t] = sb;
    }
}

// ---------------------------------------------------------------------------
// Kernel 3: out[b,ch,i,j] = sigmoid(A[b,i]*Bv[b,j]), 16 channels per block.
// Map computed once in registers, written 16x with NT stores.
// ---------------------------------------------------------------------------
__global__ __launch_bounds__(256) void bcast_kernel(const float* __restrict__ AB,
                                                    float* __restrict__ out) {
    const int blk = blockIdx.x;      // 32 b * 64 chunks
    const int b = blk >> 6;
    const int cchunk = blk & 63;
    const int t = threadIdx.x;

    __shared__ float sA[NH];
    __shared__ float sB[NW];
    if (t < NH) sA[t] = AB[b * 128 + t];
    else if (t >= 64 && t < 64 + NW) sB[t - 64] = AB[b * 128 + t];
    __syncthreads();

    nfloat4 v[4];
#pragma unroll
    for (int it = 0; it < 4; ++it) {
        const int idx = t + it * 256;          // float4 index in the 784-map
        if (idx < HW4) {
            const int r  = idx / 14;
            const int cb = (idx - r * 14) * 4;
            const float a = sA[r];
            nfloat4 q;
            q.x = 1.0f / (1.0f + expf(-(a * sB[cb + 0])));
            q.y = 1.0f / (1.0f + expf(-(a * sB[cb + 1])));
            q.z = 1.0f / (1.0f + expf(-(a * sB[cb + 2])));
            q.w = 1.0f / (1.0f + expf(-(a * sB[cb + 3])));
            v[it] = q;
        }
    }

    const size_t base = ((size_t)b * NC + (size_t)cchunk * 16) * HW4; // float4 units
#pragma unroll
    for (int ch = 0; ch < 16; ++ch) {
        nfloat4* orow = (nfloat4*)out + base + (size_t)ch * HW4;
#pragma unroll
        for (int it = 0; it < 4; ++it) {
            const int idx = t + it * 256;
            if (idx < HW4) __builtin_nontemporal_store(v[it], &orow[idx]);
        }
    }
}

// ---------------------------------------------------------------------------
extern "C" void kernel_launch(void* const* d_in, const int* in_sizes, int n_in,
                              void* d_out, int out_size, void* d_ws, size_t ws_size,
                              hipStream_t stream) {
    const float* x  = (const float*)d_in[0];
    const float* W1 = (const float*)d_in[1];
    const float* W2 = (const float*)d_in[2];
    const float* WA = (const float*)d_in[3];
    const float* bA = (const float*)d_in[4];
    const float* WB = (const float*)d_in[5];
    const float* bB = (const float*)d_in[6];
    float* out = (float*)d_out;

    float* y  = (float*)d_ws;            // BATCH*NC floats
    float* AB = y + BATCH * NC;          // BATCH*128 floats

    gap_kernel<<<BATCH * NC / 4, 256, 0, stream>>>(x, y);
    mlp_kernel<<<BATCH, 1024, 0, stream>>>(y, W1, W2, WA, bA, WB, bB, AB);
    bcast_kernel<<<BATCH * (NC / 16), 256, 0, stream>>>(AB, out);
}